// Round 1
// baseline (361.804 us; speedup 1.0000x reference)
//
#include <hip/hip_runtime.h>

#define T_SEQ 4096
#define NBATCH 4
#define CDIM 1024
#define NHEAD 64
#define SCALE (1.0f / 32.0f)
#define BT (NBATCH * T_SEQ)

typedef __bf16 bf16x8 __attribute__((ext_vector_type(8)));
typedef float f32x4 __attribute__((ext_vector_type(4)));

__device__ __forceinline__ short f2bf(float f) {
  union { float f; unsigned u; } x;
  x.f = f;
  unsigned r = x.u + 0x7FFFu + ((x.u >> 16) & 1u);
  return (short)(r >> 16);
}

__device__ __forceinline__ f32x4 mfma16(bf16x8 a, bf16x8 b, f32x4 c) {
  return __builtin_amdgcn_mfma_f32_16x16x32_bf16(a, b, c, 0, 0, 0);
}

// ---------------------------------------------------------------------------
// Kernel 1: Wt[c][k] = W*(k, c%64) * (c<64 ? SCALE : 1), bf16, c in [0,192)
// ---------------------------------------------------------------------------
__global__ void prep_w(const float* __restrict__ Wq, const float* __restrict__ Wk,
                       const float* __restrict__ Wv, short* __restrict__ Wt) {
  int c = blockIdx.x;
  const float* W = (c < 64) ? Wq : (c < 128) ? Wk : Wv;
  int cc = c & 63;
  float sc = (c < 64) ? SCALE : 1.0f;
  for (int k = threadIdx.x; k < CDIM; k += blockDim.x)
    Wt[c * CDIM + k] = f2bf(W[k * NHEAD + cc] * sc);
}

// ---------------------------------------------------------------------------
// Kernel 2: fused QKV projection. Block = 256 thr (4 waves), M-tile = 64 rows.
// Wave w computes cols [48w, 48w+48) for all 64 rows. x staged in LDS (bf16).
// Writes q,k row-major [BT][64] bf16; v transposed [64][BT] bf16.
// ---------------------------------------------------------------------------
__global__ __launch_bounds__(256) void proj_qkv(
    const float* __restrict__ x, const short* __restrict__ Wt,
    short* __restrict__ qws, short* __restrict__ kws, short* __restrict__ vtws) {
  __shared__ short xlds[64 * 40];  // stride 40 bf16 (80B): <=2-way bank aliasing
  const int tid = threadIdx.x;
  const int lane = tid & 63;
  const int w = tid >> 6;
  const int g = lane >> 4;
  const int c15 = lane & 15;
  const int rb = blockIdx.x * 64;

  f32x4 acc[4][3];
  for (int i = 0; i < 4; i++)
    for (int j = 0; j < 3; j++) acc[i][j] = (f32x4){0.f, 0.f, 0.f, 0.f};

  const int sr = tid >> 2;         // staging row 0..63
  const int sk = (tid & 3) * 8;    // staging k-offset within 32-chunk

  for (int k0 = 0; k0 < CDIM; k0 += 32) {
    const float4* xp = (const float4*)(x + (size_t)(rb + sr) * CDIM + k0 + sk);
    float4 f0 = xp[0];
    float4 f1 = xp[1];
    short pk[8];
    pk[0] = f2bf(f0.x); pk[1] = f2bf(f0.y); pk[2] = f2bf(f0.z); pk[3] = f2bf(f0.w);
    pk[4] = f2bf(f1.x); pk[5] = f2bf(f1.y); pk[6] = f2bf(f1.z); pk[7] = f2bf(f1.w);
    *(bf16x8*)&xlds[sr * 40 + (tid & 3) * 8] = *(bf16x8*)pk;
    __syncthreads();

    bf16x8 a[4];
    for (int mt = 0; mt < 4; mt++)
      a[mt] = *(bf16x8*)&xlds[(mt * 16 + c15) * 40 + g * 8];
    for (int bn = 0; bn < 3; bn++) {
      int col = w * 48 + bn * 16 + c15;
      bf16x8 bfrag = *(const bf16x8*)&Wt[(size_t)col * CDIM + k0 + g * 8];
      for (int mt = 0; mt < 4; mt++)
        acc[mt][bn] = mfma16(a[mt], bfrag, acc[mt][bn]);
    }
    __syncthreads();
  }

  for (int mt = 0; mt < 4; mt++)
    for (int bn = 0; bn < 3; bn++) {
      int col = w * 48 + bn * 16 + c15;
      int row0 = rb + mt * 16 + 4 * g;
      for (int r = 0; r < 4; r++) {
        short v = f2bf(acc[mt][bn][r]);
        int t = row0 + r;
        if (col < 64)
          qws[(size_t)t * 64 + col] = v;
        else if (col < 128)
          kws[(size_t)t * 64 + (col - 64)] = v;
        else
          vtws[(size_t)(col - 128) * BT + t] = v;
      }
    }
}

// ---------------------------------------------------------------------------
// Kernel 3: causal flash attention. 1 wave/block, 32 q-rows/wave.
// S-frag: row=q (4g+r + 16mi), col=key (lane&15 + 16kn). Online softmax over
// 16-lane groups. P goes through XOR-swizzled LDS to become the PV A-fragment.
// ---------------------------------------------------------------------------
__global__ __launch_bounds__(64) void attn_fwd(
    const short* __restrict__ qws, const short* __restrict__ kws,
    const short* __restrict__ vtws, float* __restrict__ out) {
  __shared__ short plds[32 * 40];
  const int lane = threadIdx.x;
  const int g = lane >> 4;
  const int c = lane & 15;
  const int bi = blockIdx.x;
  const int b = bi >> 7;
  const int rr = bi & 127;
  // pair light(i) with heavy(127-i) q-tiles for causal load balance
  const int qt = (rr & 1) ? (127 - (rr >> 1)) : (rr >> 1);
  const int qb = qt * 32;
  const size_t rowbase = (size_t)b * T_SEQ;

  bf16x8 qf[2][2];
  for (int mi = 0; mi < 2; mi++)
    for (int hc = 0; hc < 2; hc++)
      qf[mi][hc] =
          *(const bf16x8*)&qws[(rowbase + qb + mi * 16 + c) * 64 + hc * 32 + g * 8];

  f32x4 o[2][4];
  float mrow[2][4], rsum[2][4];
  for (int mi = 0; mi < 2; mi++) {
    for (int nt = 0; nt < 4; nt++) o[mi][nt] = (f32x4){0.f, 0.f, 0.f, 0.f};
    for (int r = 0; r < 4; r++) {
      mrow[mi][r] = -1e30f;
      rsum[mi][r] = 0.f;
    }
  }

  const int nsteps = qb / 32 + 1;
  for (int st = 0; st < nsteps; ++st) {
    const int kt = st * 32;
    bf16x8 kf[2][2];
    for (int kn = 0; kn < 2; kn++)
      for (int hc = 0; hc < 2; hc++)
        kf[kn][hc] = *(const bf16x8*)&kws[(rowbase + kt + kn * 16 + c) * 64 +
                                          hc * 32 + g * 8];
    f32x4 sv[2][2];
    for (int mi = 0; mi < 2; mi++)
      for (int kn = 0; kn < 2; kn++) {
        f32x4 z = (f32x4){0.f, 0.f, 0.f, 0.f};
        z = mfma16(qf[mi][0], kf[kn][0], z);
        sv[mi][kn] = mfma16(qf[mi][1], kf[kn][1], z);
      }

    if (st == nsteps - 1) {  // diagonal tile: causal mask
      for (int mi = 0; mi < 2; mi++)
        for (int kn = 0; kn < 2; kn++)
          for (int r = 0; r < 4; r++) {
            int key = kt + kn * 16 + c;
            int qr = qb + mi * 16 + 4 * g + r;
            if (key > qr) sv[mi][kn][r] = -1e30f;
          }
    }

    for (int mi = 0; mi < 2; mi++) {
      float t4[4], a4[4], u4[4];
      for (int r = 0; r < 4; r++) t4[r] = fmaxf(sv[mi][0][r], sv[mi][1][r]);
      for (int mk = 1; mk < 16; mk <<= 1)
        for (int r = 0; r < 4; r++) t4[r] = fmaxf(t4[r], __shfl_xor(t4[r], mk));
      for (int r = 0; r < 4; r++) {
        float mn = fmaxf(mrow[mi][r], t4[r]);
        a4[r] = __expf(mrow[mi][r] - mn);
        mrow[mi][r] = mn;
      }
      for (int kn = 0; kn < 2; kn++)
        for (int r = 0; r < 4; r++)
          sv[mi][kn][r] = __expf(sv[mi][kn][r] - mrow[mi][r]);
      for (int r = 0; r < 4; r++) u4[r] = sv[mi][0][r] + sv[mi][1][r];
      for (int mk = 1; mk < 16; mk <<= 1)
        for (int r = 0; r < 4; r++) u4[r] += __shfl_xor(u4[r], mk);
      for (int r = 0; r < 4; r++) rsum[mi][r] = rsum[mi][r] * a4[r] + u4[r];
      for (int nt = 0; nt < 4; nt++)
        for (int r = 0; r < 4; r++) o[mi][nt][r] *= a4[r];
      // P -> LDS (bf16), XOR slot swizzle within each 80B row
      for (int kn = 0; kn < 2; kn++)
        for (int r = 0; r < 4; r++) {
          int prow = mi * 16 + 4 * g + r;
          int pcol = kn * 16 + c;
          int slot = (pcol >> 3) ^ (prow & 3);
          plds[prow * 40 + slot * 8 + (pcol & 7)] = f2bf(sv[mi][kn][r]);
        }
    }

    // PV: A-frag from LDS (keys 8g..8g+7 contiguous), B-frag = V^T rows
    bf16x8 pa[2];
    for (int mi = 0; mi < 2; mi++) {
      int prow = mi * 16 + c;
      int slot = g ^ (prow & 3);
      pa[mi] = *(bf16x8*)&plds[prow * 40 + slot * 8];
    }
    for (int nt = 0; nt < 4; nt++) {
      bf16x8 vf =
          *(const bf16x8*)&vtws[(size_t)(nt * 16 + c) * BT + rowbase + kt + g * 8];
      for (int mi = 0; mi < 2; mi++) o[mi][nt] = mfma16(pa[mi], vf, o[mi][nt]);
    }
  }

  for (int mi = 0; mi < 2; mi++)
    for (int nt = 0; nt < 4; nt++)
      for (int r = 0; r < 4; r++)
        out[(rowbase + qb + mi * 16 + 4 * g + r) * 64 + nt * 16 + c] =
            o[mi][nt][r] / rsum[mi][r];
}

// ---------------------------------------------------------------------------
extern "C" void kernel_launch(void* const* d_in, const int* in_sizes, int n_in,
                              void* d_out, int out_size, void* d_ws, size_t ws_size,
                              hipStream_t stream) {
  const float* x = (const float*)d_in[0];
  const float* Wq = (const float*)d_in[1];
  const float* Wk = (const float*)d_in[2];
  const float* Wv = (const float*)d_in[3];
  float* out = (float*)d_out;

  char* ws = (char*)d_ws;
  short* Wt = (short*)(ws);                            // 192*1024*2 = 384 KB
  short* qws = (short*)(ws + 393216);                  // 2 MB
  short* kws = (short*)(ws + 393216 + 2097152);        // 2 MB
  short* vtws = (short*)(ws + 393216 + 2 * 2097152);   // 2 MB

  prep_w<<<dim3(192), dim3(256), 0, stream>>>(Wq, Wk, Wv, Wt);
  proj_qkv<<<dim3(256), dim3(256), 0, stream>>>(x, Wt, qws, kws, vtws);
  attn_fwd<<<dim3(512), dim3(64), 0, stream>>>(qws, kws, vtws, out);
}

// Round 2
// 237.280 us; speedup vs baseline: 1.5248x; 1.5248x over previous
//
#include <hip/hip_runtime.h>

#define T_SEQ 4096
#define NBATCH 4
#define CDIM 1024
#define NHEAD 64
#define SCALE (1.0f / 32.0f)
#define BT (NBATCH * T_SEQ)
#define NW 8  // waves per attn block (key-split factor)

typedef __bf16 bf16x8 __attribute__((ext_vector_type(8)));
typedef float f32x4 __attribute__((ext_vector_type(4)));

__device__ __forceinline__ short f2bf(float f) {
  union { float f; unsigned u; } x;
  x.f = f;
  unsigned r = x.u + 0x7FFFu + ((x.u >> 16) & 1u);
  return (short)(r >> 16);
}

__device__ __forceinline__ f32x4 mfma16(bf16x8 a, bf16x8 b, f32x4 c) {
  return __builtin_amdgcn_mfma_f32_16x16x32_bf16(a, b, c, 0, 0, 0);
}

// ---------------------------------------------------------------------------
// Kernel 1: Wt[c][k] = W*(k, c%64) * (c<64 ? SCALE : 1), bf16, c in [0,192)
// ---------------------------------------------------------------------------
__global__ void prep_w(const float* __restrict__ Wq, const float* __restrict__ Wk,
                       const float* __restrict__ Wv, short* __restrict__ Wt) {
  int c = blockIdx.x;
  const float* W = (c < 64) ? Wq : (c < 128) ? Wk : Wv;
  int cc = c & 63;
  float sc = (c < 64) ? SCALE : 1.0f;
  for (int k = threadIdx.x; k < CDIM; k += blockDim.x)
    Wt[c * CDIM + k] = f2bf(W[k * NHEAD + cc] * sc);
}

// ---------------------------------------------------------------------------
// Kernel 2: fused QKV projection. Block = 256 thr (4 waves), M-tile = 32 rows
// (512 blocks -> 2 blocks/CU). Wave w computes cols [48w,48w+48).
// Writes q,k row-major [BT][64] bf16; v transposed [64][BT] bf16.
// ---------------------------------------------------------------------------
__global__ __launch_bounds__(256) void proj_qkv(
    const float* __restrict__ x, const short* __restrict__ Wt,
    short* __restrict__ qws, short* __restrict__ kws, short* __restrict__ vtws) {
  __shared__ short xlds[32 * 40];  // stride 40 bf16 (80B)
  const int tid = threadIdx.x;
  const int lane = tid & 63;
  const int w = tid >> 6;
  const int g = lane >> 4;
  const int c15 = lane & 15;
  const int rb = blockIdx.x * 32;

  f32x4 acc[2][3];
  for (int i = 0; i < 2; i++)
    for (int j = 0; j < 3; j++) acc[i][j] = (f32x4){0.f, 0.f, 0.f, 0.f};

  const int sr = tid >> 3;         // staging row 0..31
  const int sk = (tid & 7) * 4;    // staging k-offset within 32-chunk

  for (int k0 = 0; k0 < CDIM; k0 += 32) {
    float4 f0 = *(const float4*)(x + (size_t)(rb + sr) * CDIM + k0 + sk);
    short pk[4];
    pk[0] = f2bf(f0.x); pk[1] = f2bf(f0.y); pk[2] = f2bf(f0.z); pk[3] = f2bf(f0.w);
    *(uint2*)&xlds[sr * 40 + sk] = *(uint2*)pk;
    __syncthreads();

    bf16x8 a[2];
    for (int mt = 0; mt < 2; mt++)
      a[mt] = *(bf16x8*)&xlds[(mt * 16 + c15) * 40 + g * 8];
    for (int bn = 0; bn < 3; bn++) {
      int col = w * 48 + bn * 16 + c15;
      bf16x8 bfrag = *(const bf16x8*)&Wt[(size_t)col * CDIM + k0 + g * 8];
      for (int mt = 0; mt < 2; mt++)
        acc[mt][bn] = mfma16(a[mt], bfrag, acc[mt][bn]);
    }
    __syncthreads();
  }

  for (int mt = 0; mt < 2; mt++)
    for (int bn = 0; bn < 3; bn++) {
      int col = w * 48 + bn * 16 + c15;
      int row0 = rb + mt * 16 + 4 * g;
      for (int r = 0; r < 4; r++) {
        short v = f2bf(acc[mt][bn][r]);
        int t = row0 + r;
        if (col < 64)
          qws[(size_t)t * 64 + col] = v;
        else if (col < 128)
          kws[(size_t)t * 64 + (col - 64)] = v;
        else
          vtws[(size_t)(col - 128) * BT + t] = v;
      }
    }
}

// ---------------------------------------------------------------------------
// Kernel 3: causal flash attention, in-block split-K.
// Block = 8 waves (512 thr), one 32-row q-tile per block; wave w processes
// key-steps st = w, w+8, ... with private (m,l,o) online-softmax state and
// double-buffered K/V register prefetch. Epilogue: per-wave partials -> LDS,
// one barrier, LSE-merge across 8 waves.
// Per-wave LDS region (8448 B): [0,2560) P-tile (reused), then o[32][64] f32
// at [0,8192) after loop, m[32] at 8192, l[32] at 8320.
// ---------------------------------------------------------------------------
__global__ __launch_bounds__(512, 4) void attn_fwd(
    const short* __restrict__ qws, const short* __restrict__ kws,
    const short* __restrict__ vtws, float* __restrict__ out) {
  __shared__ __align__(16) char smem[NW * 8448];
  const int tid = threadIdx.x;
  const int lane = tid & 63;
  const int w = tid >> 6;
  const int g = lane >> 4;
  const int c = lane & 15;
  const int bi = blockIdx.x;
  const int b = bi >> 7;
  const int qt = bi & 127;
  const int qb = qt * 32;
  const size_t rowbase = (size_t)b * T_SEQ;
  const int nsteps = qt + 1;

  short* plds = (short*)(smem + w * 8448);

  bf16x8 qf[2][2];
  for (int mi = 0; mi < 2; mi++)
    for (int hc = 0; hc < 2; hc++)
      qf[mi][hc] =
          *(const bf16x8*)&qws[(rowbase + qb + mi * 16 + c) * 64 + hc * 32 + g * 8];

  f32x4 o[2][4];
  float mrow[2][4], rsum[2][4];
  for (int mi = 0; mi < 2; mi++) {
    for (int nt = 0; nt < 4; nt++) o[mi][nt] = (f32x4){0.f, 0.f, 0.f, 0.f};
    for (int r = 0; r < 4; r++) {
      mrow[mi][r] = -1e30f;
      rsum[mi][r] = 0.f;
    }
  }

  int st = w;
  bf16x8 kc[2][2], vc[4];
  if (st < nsteps) {
    const int kt = st * 32;
    for (int kn = 0; kn < 2; kn++)
      for (int hc = 0; hc < 2; hc++)
        kc[kn][hc] = *(const bf16x8*)&kws[(rowbase + kt + kn * 16 + c) * 64 +
                                          hc * 32 + g * 8];
    for (int nt = 0; nt < 4; nt++)
      vc[nt] = *(const bf16x8*)&vtws[(size_t)(nt * 16 + c) * BT + rowbase + kt + g * 8];
  }

  for (; st < nsteps; st += NW) {
    const int kt = st * 32;
    const int stn = st + NW;
    // prefetch next step's K/V while this step's VALU runs
    bf16x8 kn_[2][2], vn_[4];
    if (stn < nsteps) {
      const int ktn = stn * 32;
      for (int kn = 0; kn < 2; kn++)
        for (int hc = 0; hc < 2; hc++)
          kn_[kn][hc] = *(const bf16x8*)&kws[(rowbase + ktn + kn * 16 + c) * 64 +
                                             hc * 32 + g * 8];
      for (int nt = 0; nt < 4; nt++)
        vn_[nt] =
            *(const bf16x8*)&vtws[(size_t)(nt * 16 + c) * BT + rowbase + ktn + g * 8];
    }

    f32x4 sv[2][2];
    for (int mi = 0; mi < 2; mi++)
      for (int kn = 0; kn < 2; kn++) {
        f32x4 z = (f32x4){0.f, 0.f, 0.f, 0.f};
        z = mfma16(qf[mi][0], kc[kn][0], z);
        sv[mi][kn] = mfma16(qf[mi][1], kc[kn][1], z);
      }

    if (st == nsteps - 1) {  // diagonal tile: causal mask
      for (int mi = 0; mi < 2; mi++)
        for (int kn = 0; kn < 2; kn++)
          for (int r = 0; r < 4; r++) {
            int key = kt + kn * 16 + c;
            int qr = qb + mi * 16 + 4 * g + r;
            if (key > qr) sv[mi][kn][r] = -1e30f;
          }
    }

    for (int mi = 0; mi < 2; mi++) {
      float t4[4], a4[4], u4[4];
      for (int r = 0; r < 4; r++) t4[r] = fmaxf(sv[mi][0][r], sv[mi][1][r]);
      for (int mk = 1; mk < 16; mk <<= 1)
        for (int r = 0; r < 4; r++) t4[r] = fmaxf(t4[r], __shfl_xor(t4[r], mk));
      for (int r = 0; r < 4; r++) {
        float mn = fmaxf(mrow[mi][r], t4[r]);
        a4[r] = __expf(mrow[mi][r] - mn);
        mrow[mi][r] = mn;
      }
      for (int kn = 0; kn < 2; kn++)
        for (int r = 0; r < 4; r++)
          sv[mi][kn][r] = __expf(sv[mi][kn][r] - mrow[mi][r]);
      for (int r = 0; r < 4; r++) u4[r] = sv[mi][0][r] + sv[mi][1][r];
      for (int mk = 1; mk < 16; mk <<= 1)
        for (int r = 0; r < 4; r++) u4[r] += __shfl_xor(u4[r], mk);
      for (int r = 0; r < 4; r++) rsum[mi][r] = rsum[mi][r] * a4[r] + u4[r];
      for (int nt = 0; nt < 4; nt++)
        for (int r = 0; r < 4; r++) o[mi][nt][r] *= a4[r];
      // P -> per-wave LDS (bf16), XOR slot swizzle within each 80B row
      for (int kn = 0; kn < 2; kn++)
        for (int r = 0; r < 4; r++) {
          int prow = mi * 16 + 4 * g + r;
          int pcol = kn * 16 + c;
          int slot = (pcol >> 3) ^ (prow & 3);
          plds[prow * 40 + slot * 8 + (pcol & 7)] = f2bf(sv[mi][kn][r]);
        }
    }

    // PV: A-frag from per-wave LDS, B-frag = V^T rows (prefetched)
    bf16x8 pa[2];
    for (int mi = 0; mi < 2; mi++) {
      int prow = mi * 16 + c;
      int slot = g ^ (prow & 3);
      pa[mi] = *(bf16x8*)&plds[prow * 40 + slot * 8];
    }
    for (int nt = 0; nt < 4; nt++)
      for (int mi = 0; mi < 2; mi++) o[mi][nt] = mfma16(pa[mi], vc[nt], o[mi][nt]);

    for (int kn = 0; kn < 2; kn++)
      for (int hc = 0; hc < 2; hc++) kc[kn][hc] = kn_[kn][hc];
    for (int nt = 0; nt < 4; nt++) vc[nt] = vn_[nt];
  }

  // ---- write per-wave partials (plds region is dead now) ----
  float* ow = (float*)(smem + w * 8448);
  float* mw = (float*)(smem + w * 8448 + 8192);
  float* lw = (float*)(smem + w * 8448 + 8320);
  for (int mi = 0; mi < 2; mi++)
    for (int nt = 0; nt < 4; nt++)
      for (int r = 0; r < 4; r++)
        ow[(mi * 16 + 4 * g + r) * 64 + nt * 16 + c] = o[mi][nt][r];
  if (c == 0)
    for (int mi = 0; mi < 2; mi++)
      for (int r = 0; r < 4; r++) {
        mw[mi * 16 + 4 * g + r] = mrow[mi][r];
        lw[mi * 16 + 4 * g + r] = rsum[mi][r];
      }
  __syncthreads();

  // ---- LSE-merge across the 8 waves: 512 thr x 4 elems = 32x64 outputs ----
  for (int i = 0; i < 4; i++) {
    int e = tid + i * 512;
    int row = e >> 6;
    int d = e & 63;
    float M = -1e30f;
    for (int ww = 0; ww < NW; ww++)
      M = fmaxf(M, *(const float*)(smem + ww * 8448 + 8192 + row * 4));
    float L = 0.f, O = 0.f;
    for (int ww = 0; ww < NW; ww++) {
      float mv = *(const float*)(smem + ww * 8448 + 8192 + row * 4);
      float f = __expf(mv - M);
      L += f * *(const float*)(smem + ww * 8448 + 8320 + row * 4);
      O += f * *(const float*)(smem + ww * 8448 + (row * 64 + d) * 4);
    }
    out[(rowbase + qb + row) * 64 + d] = O / L;
  }
}

// ---------------------------------------------------------------------------
extern "C" void kernel_launch(void* const* d_in, const int* in_sizes, int n_in,
                              void* d_out, int out_size, void* d_ws, size_t ws_size,
                              hipStream_t stream) {
  const float* x = (const float*)d_in[0];
  const float* Wq = (const float*)d_in[1];
  const float* Wk = (const float*)d_in[2];
  const float* Wv = (const float*)d_in[3];
  float* out = (float*)d_out;

  char* ws = (char*)d_ws;
  short* Wt = (short*)(ws);                            // 192*1024*2 = 384 KB
  short* qws = (short*)(ws + 393216);                  // 2 MB
  short* kws = (short*)(ws + 393216 + 2097152);        // 2 MB
  short* vtws = (short*)(ws + 393216 + 2 * 2097152);   // 2 MB

  prep_w<<<dim3(192), dim3(256), 0, stream>>>(Wq, Wk, Wv, Wt);
  proj_qkv<<<dim3(512), dim3(256), 0, stream>>>(x, Wt, qws, kws, vtws);
  attn_fwd<<<dim3(512), dim3(512), 0, stream>>>(qws, kws, vtws, out);
}

// Round 3
// 120.997 us; speedup vs baseline: 2.9902x; 1.9610x over previous
//
#include <hip/hip_runtime.h>

#define T_SEQ 4096
#define NBATCH 4
#define CDIM 1024
#define NHEAD 64
#define SCALE (1.0f / 32.0f)
#define BT (NBATCH * T_SEQ)
#define NW 8  // waves per attn block (key-split factor)

typedef __bf16 bf16x8 __attribute__((ext_vector_type(8)));
typedef float f32x4 __attribute__((ext_vector_type(4)));

__device__ __forceinline__ short f2bf(float f) {
  union { float f; unsigned u; } x;
  x.f = f;
  unsigned r = x.u + 0x7FFFu + ((x.u >> 16) & 1u);
  return (short)(r >> 16);
}

__device__ __forceinline__ f32x4 mfma16(bf16x8 a, bf16x8 b, f32x4 c) {
  return __builtin_amdgcn_mfma_f32_16x16x32_bf16(a, b, c, 0, 0, 0);
}

// ---------------------------------------------------------------------------
// Kernel 1: Wt[c][k] = W*(k, c%64) * (c<64 ? SCALE : 1), bf16, c in [0,192)
// ---------------------------------------------------------------------------
__global__ void prep_w(const float* __restrict__ Wq, const float* __restrict__ Wk,
                       const float* __restrict__ Wv, short* __restrict__ Wt) {
  int c = blockIdx.x;
  const float* W = (c < 64) ? Wq : (c < 128) ? Wk : Wv;
  int cc = c & 63;
  float sc = (c < 64) ? SCALE : 1.0f;
  for (int k = threadIdx.x; k < CDIM; k += blockDim.x)
    Wt[c * CDIM + k] = f2bf(W[k * NHEAD + cc] * sc);
}

// ---------------------------------------------------------------------------
// Kernel 2: fused QKV projection. Block = 256 thr (4 waves), M-tile = 32 rows
// (512 blocks -> 2 blocks/CU). Wave w computes cols [48w,48w+48).
// Writes q,k row-major [BT][64] bf16; v transposed [64][BT] bf16.
// ---------------------------------------------------------------------------
__global__ __launch_bounds__(256) void proj_qkv(
    const float* __restrict__ x, const short* __restrict__ Wt,
    short* __restrict__ qws, short* __restrict__ kws, short* __restrict__ vtws) {
  __shared__ short xlds[32 * 40];  // stride 40 bf16 (80B)
  const int tid = threadIdx.x;
  const int lane = tid & 63;
  const int w = tid >> 6;
  const int g = lane >> 4;
  const int c15 = lane & 15;
  const int rb = blockIdx.x * 32;

  f32x4 acc[2][3];
  for (int i = 0; i < 2; i++)
    for (int j = 0; j < 3; j++) acc[i][j] = (f32x4){0.f, 0.f, 0.f, 0.f};

  const int sr = tid >> 3;         // staging row 0..31
  const int sk = (tid & 7) * 4;    // staging k-offset within 32-chunk

  for (int k0 = 0; k0 < CDIM; k0 += 32) {
    float4 f0 = *(const float4*)(x + (size_t)(rb + sr) * CDIM + k0 + sk);
    short pk[4];
    pk[0] = f2bf(f0.x); pk[1] = f2bf(f0.y); pk[2] = f2bf(f0.z); pk[3] = f2bf(f0.w);
    *(uint2*)&xlds[sr * 40 + sk] = *(uint2*)pk;
    __syncthreads();

    bf16x8 a[2];
    for (int mt = 0; mt < 2; mt++)
      a[mt] = *(bf16x8*)&xlds[(mt * 16 + c15) * 40 + g * 8];
    for (int bn = 0; bn < 3; bn++) {
      int col = w * 48 + bn * 16 + c15;
      bf16x8 bfrag = *(const bf16x8*)&Wt[(size_t)col * CDIM + k0 + g * 8];
      for (int mt = 0; mt < 2; mt++)
        acc[mt][bn] = mfma16(a[mt], bfrag, acc[mt][bn]);
    }
    __syncthreads();
  }

  for (int mt = 0; mt < 2; mt++)
    for (int bn = 0; bn < 3; bn++) {
      int col = w * 48 + bn * 16 + c15;
      int row0 = rb + mt * 16 + 4 * g;
      for (int r = 0; r < 4; r++) {
        short v = f2bf(acc[mt][bn][r]);
        int t = row0 + r;
        if (col < 64)
          qws[(size_t)t * 64 + col] = v;
        else if (col < 128)
          kws[(size_t)t * 64 + (col - 64)] = v;
        else
          vtws[(size_t)(col - 128) * BT + t] = v;
      }
    }
}

// ---------------------------------------------------------------------------
// Kernel 3: causal flash attention, in-block split-K.
// Block = 8 waves (512 thr), one 32-row q-tile per block; wave w processes
// key-steps st = w, w+8, ... with private (m,l,o) online-softmax state.
// K/V loaded at step top (V latency hides under QK+softmax; K under TLP).
// Epilogue: per-wave partials -> LDS, one barrier, LSE-merge across 8 waves.
// Per-wave LDS region (8448 B): [0,2560) P-tile (reused), then o[32][64] f32
// at [0,8192) after loop, m[32] at 8192, l[32] at 8320.
// __launch_bounds__(512,2): VGPR cap 256 — R2's (512,4) capped at 64+64 and
// spilled to scratch (246 MB WRITE, 108 MB FETCH, 30k cy/step).
// ---------------------------------------------------------------------------
__global__ __launch_bounds__(512, 2) void attn_fwd(
    const short* __restrict__ qws, const short* __restrict__ kws,
    const short* __restrict__ vtws, float* __restrict__ out) {
  __shared__ __align__(16) char smem[NW * 8448];
  const int tid = threadIdx.x;
  const int lane = tid & 63;
  const int w = tid >> 6;
  const int g = lane >> 4;
  const int c = lane & 15;
  const int bi = blockIdx.x;
  const int b = bi >> 7;
  const int qt = bi & 127;
  const int qb = qt * 32;
  const size_t rowbase = (size_t)b * T_SEQ;
  const int nsteps = qt + 1;

  short* plds = (short*)(smem + w * 8448);

  bf16x8 qf[2][2];
  for (int mi = 0; mi < 2; mi++)
    for (int hc = 0; hc < 2; hc++)
      qf[mi][hc] =
          *(const bf16x8*)&qws[(rowbase + qb + mi * 16 + c) * 64 + hc * 32 + g * 8];

  f32x4 o[2][4];
  float mrow[2][4], rsum[2][4];
  for (int mi = 0; mi < 2; mi++) {
    for (int nt = 0; nt < 4; nt++) o[mi][nt] = (f32x4){0.f, 0.f, 0.f, 0.f};
    for (int r = 0; r < 4; r++) {
      mrow[mi][r] = -1e30f;
      rsum[mi][r] = 0.f;
    }
  }

  for (int st = w; st < nsteps; st += NW) {
    const int kt = st * 32;
    // K and V for this step: issue all loads up front. V is consumed last
    // (PV), so its latency hides under QK^T + softmax.
    bf16x8 kc[2][2], vc[4];
    for (int kn = 0; kn < 2; kn++)
      for (int hc = 0; hc < 2; hc++)
        kc[kn][hc] = *(const bf16x8*)&kws[(rowbase + kt + kn * 16 + c) * 64 +
                                          hc * 32 + g * 8];
    for (int nt = 0; nt < 4; nt++)
      vc[nt] = *(const bf16x8*)&vtws[(size_t)(nt * 16 + c) * BT + rowbase + kt + g * 8];

    f32x4 sv[2][2];
    for (int mi = 0; mi < 2; mi++)
      for (int kn = 0; kn < 2; kn++) {
        f32x4 z = (f32x4){0.f, 0.f, 0.f, 0.f};
        z = mfma16(qf[mi][0], kc[kn][0], z);
        sv[mi][kn] = mfma16(qf[mi][1], kc[kn][1], z);
      }

    if (st == nsteps - 1) {  // diagonal tile: causal mask
      for (int mi = 0; mi < 2; mi++)
        for (int kn = 0; kn < 2; kn++)
          for (int r = 0; r < 4; r++) {
            int key = kt + kn * 16 + c;
            int qr = qb + mi * 16 + 4 * g + r;
            if (key > qr) sv[mi][kn][r] = -1e30f;
          }
    }

    for (int mi = 0; mi < 2; mi++) {
      float t4[4], a4[4], u4[4];
      for (int r = 0; r < 4; r++) t4[r] = fmaxf(sv[mi][0][r], sv[mi][1][r]);
      for (int mk = 1; mk < 16; mk <<= 1)
        for (int r = 0; r < 4; r++) t4[r] = fmaxf(t4[r], __shfl_xor(t4[r], mk));
      for (int r = 0; r < 4; r++) {
        float mn = fmaxf(mrow[mi][r], t4[r]);
        a4[r] = __expf(mrow[mi][r] - mn);
        mrow[mi][r] = mn;
      }
      for (int kn = 0; kn < 2; kn++)
        for (int r = 0; r < 4; r++)
          sv[mi][kn][r] = __expf(sv[mi][kn][r] - mrow[mi][r]);
      for (int r = 0; r < 4; r++) u4[r] = sv[mi][0][r] + sv[mi][1][r];
      for (int mk = 1; mk < 16; mk <<= 1)
        for (int r = 0; r < 4; r++) u4[r] += __shfl_xor(u4[r], mk);
      for (int r = 0; r < 4; r++) rsum[mi][r] = rsum[mi][r] * a4[r] + u4[r];
      for (int nt = 0; nt < 4; nt++)
        for (int r = 0; r < 4; r++) o[mi][nt][r] *= a4[r];
      // P -> per-wave LDS (bf16), XOR slot swizzle within each 80B row
      for (int kn = 0; kn < 2; kn++)
        for (int r = 0; r < 4; r++) {
          int prow = mi * 16 + 4 * g + r;
          int pcol = kn * 16 + c;
          int slot = (pcol >> 3) ^ (prow & 3);
          plds[prow * 40 + slot * 8 + (pcol & 7)] = f2bf(sv[mi][kn][r]);
        }
    }

    // PV: A-frag from per-wave LDS, B-frag = V^T rows
    bf16x8 pa[2];
    for (int mi = 0; mi < 2; mi++) {
      int prow = mi * 16 + c;
      int slot = g ^ (prow & 3);
      pa[mi] = *(bf16x8*)&plds[prow * 40 + slot * 8];
    }
    for (int nt = 0; nt < 4; nt++)
      for (int mi = 0; mi < 2; mi++) o[mi][nt] = mfma16(pa[mi], vc[nt], o[mi][nt]);
  }

  // ---- write per-wave partials (plds region is dead now) ----
  float* ow = (float*)(smem + w * 8448);
  float* mw = (float*)(smem + w * 8448 + 8192);
  float* lw = (float*)(smem + w * 8448 + 8320);
  for (int mi = 0; mi < 2; mi++)
    for (int nt = 0; nt < 4; nt++)
      for (int r = 0; r < 4; r++)
        ow[(mi * 16 + 4 * g + r) * 64 + nt * 16 + c] = o[mi][nt][r];
  if (c == 0)
    for (int mi = 0; mi < 2; mi++)
      for (int r = 0; r < 4; r++) {
        mw[mi * 16 + 4 * g + r] = mrow[mi][r];
        lw[mi * 16 + 4 * g + r] = rsum[mi][r];
      }
  __syncthreads();

  // ---- LSE-merge across the 8 waves: 512 thr x 4 elems = 32x64 outputs ----
  for (int i = 0; i < 4; i++) {
    int e = tid + i * 512;
    int row = e >> 6;
    int d = e & 63;
    float M = -1e30f;
    for (int ww = 0; ww < NW; ww++)
      M = fmaxf(M, *(const float*)(smem + ww * 8448 + 8192 + row * 4));
    float L = 0.f, O = 0.f;
    for (int ww = 0; ww < NW; ww++) {
      float mv = *(const float*)(smem + ww * 8448 + 8192 + row * 4);
      float f = __expf(mv - M);
      L += f * *(const float*)(smem + ww * 8448 + 8320 + row * 4);
      O += f * *(const float*)(smem + ww * 8448 + (row * 64 + d) * 4);
    }
    out[(rowbase + qb + row) * 64 + d] = O / L;
  }
}

// ---------------------------------------------------------------------------
extern "C" void kernel_launch(void* const* d_in, const int* in_sizes, int n_in,
                              void* d_out, int out_size, void* d_ws, size_t ws_size,
                              hipStream_t stream) {
  const float* x = (const float*)d_in[0];
  const float* Wq = (const float*)d_in[1];
  const float* Wk = (const float*)d_in[2];
  const float* Wv = (const float*)d_in[3];
  float* out = (float*)d_out;

  char* ws = (char*)d_ws;
  short* Wt = (short*)(ws);                            // 192*1024*2 = 384 KB
  short* qws = (short*)(ws + 393216);                  // 2 MB
  short* kws = (short*)(ws + 393216 + 2097152);        // 2 MB
  short* vtws = (short*)(ws + 393216 + 2 * 2097152);   // 2 MB

  prep_w<<<dim3(192), dim3(256), 0, stream>>>(Wq, Wk, Wv, Wt);
  proj_qkv<<<dim3(512), dim3(256), 0, stream>>>(x, Wt, qws, kws, vtws);
  attn_fwd<<<dim3(512), dim3(512), 0, stream>>>(qws, kws, vtws, out);
}

// Round 5
// 80.249 us; speedup vs baseline: 4.5085x; 1.5078x over previous
//
#include <hip/hip_runtime.h>

#define T_SEQ 4096
#define NBATCH 4
#define CDIM 1024
#define NHEAD 64
#define SCALE (1.0f / 32.0f)
#define BT (NBATCH * T_SEQ)
#define NW 8  // waves per attn block

typedef __bf16 bf16x8 __attribute__((ext_vector_type(8)));
typedef float f32x4 __attribute__((ext_vector_type(4)));
typedef unsigned long long u64;

__device__ __forceinline__ unsigned short f2bf(float f) {
  union { float f; unsigned u; } x;
  x.f = f;
  unsigned r = x.u + 0x7FFFu + ((x.u >> 16) & 1u);
  return (unsigned short)(r >> 16);
}

__device__ __forceinline__ unsigned pack_bf16(float lo, float hi) {
  return (unsigned)f2bf(lo) | ((unsigned)f2bf(hi) << 16);
}

__device__ __forceinline__ f32x4 mfma16(bf16x8 a, bf16x8 b, f32x4 c) {
  return __builtin_amdgcn_mfma_f32_16x16x32_bf16(a, b, c, 0, 0, 0);
}

__device__ __forceinline__ bf16x8 ones8() {
  bf16x8 v;
  for (int j = 0; j < 8; ++j) v[j] = (__bf16)1.0f;
  return v;
}

// ---------------------------------------------------------------------------
// Kernel 1: Wt[c][k] = W*(k, c%64) * (c<64 ? SCALE : 1), bf16, c in [0,192)
// ---------------------------------------------------------------------------
__global__ void prep_w(const float* __restrict__ Wq, const float* __restrict__ Wk,
                       const float* __restrict__ Wv, unsigned short* __restrict__ Wt) {
  int c = blockIdx.x;
  const float* W = (c < 64) ? Wq : (c < 128) ? Wk : Wv;
  int cc = c & 63;
  float sc = (c < 64) ? SCALE : 1.0f;
  for (int k = threadIdx.x; k < CDIM; k += blockDim.x)
    Wt[c * CDIM + k] = f2bf(W[k * NHEAD + cc] * sc);
}

// ---------------------------------------------------------------------------
// Kernel 2: fused QKV projection, BK=128 with register prefetch.
// Block = 256 thr (4 waves), M-tile = 32 rows, 512 blocks.
// Writes q,k row-major [BT][64] bf16; v transposed [64][BT] bf16.
// ---------------------------------------------------------------------------
__global__ __launch_bounds__(256) void proj_qkv(
    const float* __restrict__ x, const unsigned short* __restrict__ Wt,
    unsigned short* __restrict__ qws, unsigned short* __restrict__ kws,
    unsigned short* __restrict__ vtws) {
  __shared__ unsigned short xlds[32][136];  // 128 bf16 + 8 pad
  const int tid = threadIdx.x;
  const int lane = tid & 63;
  const int w = tid >> 6;
  const int g = lane >> 4;
  const int c15 = lane & 15;
  const int rb = blockIdx.x * 32;

  f32x4 acc[2][3];
  for (int i = 0; i < 2; i++)
    for (int j = 0; j < 3; j++) acc[i][j] = (f32x4){0.f, 0.f, 0.f, 0.f};

  const int sr = tid >> 3;         // staging row 0..31
  const int sc = (tid & 7) * 16;   // staging col base (floats)
  const float* xrow = x + (size_t)(rb + sr) * CDIM + sc;

  float4 cur[4];
  for (int i = 0; i < 4; i++) cur[i] = *(const float4*)(xrow + i * 4);

  for (int k0 = 0; k0 < CDIM; k0 += 128) {
    unsigned short pk[16];
    for (int i = 0; i < 4; i++) {
      pk[i * 4 + 0] = f2bf(cur[i].x);
      pk[i * 4 + 1] = f2bf(cur[i].y);
      pk[i * 4 + 2] = f2bf(cur[i].z);
      pk[i * 4 + 3] = f2bf(cur[i].w);
    }
    *(bf16x8*)&xlds[sr][sc] = *(bf16x8*)&pk[0];
    *(bf16x8*)&xlds[sr][sc + 8] = *(bf16x8*)&pk[8];
    __syncthreads();
    if (k0 + 128 < CDIM)
      for (int i = 0; i < 4; i++)
        cur[i] = *(const float4*)(xrow + k0 + 128 + i * 4);

    for (int kk = 0; kk < 4; kk++) {
      bf16x8 a[2];
      for (int mt = 0; mt < 2; mt++)
        a[mt] = *(bf16x8*)&xlds[mt * 16 + c15][kk * 32 + g * 8];
      for (int bn = 0; bn < 3; bn++) {
        int col = w * 48 + bn * 16 + c15;
        bf16x8 bfrag =
            *(const bf16x8*)&Wt[(size_t)col * CDIM + k0 + kk * 32 + g * 8];
        for (int mt = 0; mt < 2; mt++)
          acc[mt][bn] = mfma16(a[mt], bfrag, acc[mt][bn]);
      }
    }
    __syncthreads();
  }

  for (int mt = 0; mt < 2; mt++)
    for (int bn = 0; bn < 3; bn++) {
      int col = w * 48 + bn * 16 + c15;
      int row0 = rb + mt * 16 + 4 * g;
      for (int r = 0; r < 4; r++) {
        unsigned short v = f2bf(acc[mt][bn][r]);
        int t = row0 + r;
        if (col < 64)
          qws[(size_t)t * 64 + col] = v;
        else if (col < 128)
          kws[(size_t)t * 64 + (col - 64)] = v;
        else
          vtws[(size_t)(col - 128) * BT + t] = v;
      }
    }
}

// ---------------------------------------------------------------------------
// Kernel 3: causal flash attention, swapped-operand + paired q-tiles.
// 256 blocks (4 batch x 64 pairs) x 8 waves; block does qt=pi then 127-pi
// (uniform 129 steps). S = mfma(K,Q): lane c holds q-row c, keys on 4g+r.
// Softmax state on the c-axis: row-max = 7 fmax + 2 shuffles; l via ones-MFMA
// accumulated like o; defer-max THR=8. P tile in per-wave LDS, accessed
// EXCLUSIVELY as u64 (store and load) -- R4 stored u64 / loaded bf16x8 and
// failed (absmax 4.49): TBAA no-alias let the scheduler reorder the P
// ds_read above the ds_write. Also dropped cvt_pk asm for proven f2bf packs,
// and an asm memory fence pins store->load order.
// Per-wave LDS 8448 B: P [32 rows][10 u64] during loop; partials o[32][64]
// f32 @0, m[32] @8192, l[32] @8320 after loop.
// ---------------------------------------------------------------------------
__global__ __launch_bounds__(512, 2) void attn_fwd(
    const unsigned short* __restrict__ qws, const unsigned short* __restrict__ kws,
    const unsigned short* __restrict__ vtws, float* __restrict__ out) {
  __shared__ __align__(16) char smem[NW * 8448];
  const int tid = threadIdx.x;
  const int lane = tid & 63;
  const int w = tid >> 6;
  const int g = lane >> 4;
  const int c = lane & 15;
  const int b = blockIdx.x >> 6;
  const int pi = blockIdx.x & 63;
  const size_t rowbase = (size_t)b * T_SEQ;
  char* wbase = smem + w * 8448;
  u64* pl = (u64*)wbase;  // P tile: row stride 10 u64 (80 B)
  const bf16x8 vone = ones8();

  for (int half = 0; half < 2; ++half) {
    const int qt = half ? (127 - pi) : pi;
    const int qb = qt * 32;
    const int nsteps = qt + 1;

    bf16x8 qf[2][2];
    for (int mi = 0; mi < 2; mi++)
      for (int hc = 0; hc < 2; hc++)
        qf[mi][hc] = *(const bf16x8*)&qws[(rowbase + qb + mi * 16 + c) * 64 +
                                          hc * 32 + g * 8];

    f32x4 o[2][4];
    f32x4 o5[2];
    float mrow[2];
    for (int mi = 0; mi < 2; mi++) {
      for (int nt = 0; nt < 4; nt++) o[mi][nt] = (f32x4){0.f, 0.f, 0.f, 0.f};
      o5[mi] = (f32x4){0.f, 0.f, 0.f, 0.f};
      mrow[mi] = -1e30f;
    }

    for (int st = w; st < nsteps; st += NW) {
      const int kt = st * 32;
      bf16x8 kc0[2], kc1[2], vc[4];
      for (int kn = 0; kn < 2; kn++) {
        kc0[kn] = *(const bf16x8*)&kws[(rowbase + kt + kn * 16 + c) * 64 + g * 8];
        kc1[kn] =
            *(const bf16x8*)&kws[(rowbase + kt + kn * 16 + c) * 64 + 32 + g * 8];
      }
      for (int nt = 0; nt < 4; nt++)
        vc[nt] =
            *(const bf16x8*)&vtws[(size_t)(nt * 16 + c) * BT + rowbase + kt + g * 8];

      // S = mfma(K, Q): lane c = q-row, reg r = key 4g+r (+16 kn)
      f32x4 sv[2][2];
      for (int mi = 0; mi < 2; mi++)
        for (int kn = 0; kn < 2; kn++) {
          f32x4 z = (f32x4){0.f, 0.f, 0.f, 0.f};
          z = mfma16(kc0[kn], qf[mi][0], z);
          sv[mi][kn] = mfma16(kc1[kn], qf[mi][1], z);
        }

      if (st == nsteps - 1) {  // diagonal tile: causal mask
        for (int mi = 0; mi < 2; mi++)
          for (int kn = 0; kn < 2; kn++)
            for (int r = 0; r < 4; r++) {
              int key = kt + kn * 16 + 4 * g + r;
              int qr = qb + mi * 16 + c;
              if (key > qr) sv[mi][kn][r] = -1e30f;
            }
      }

      for (int mi = 0; mi < 2; mi++) {
        float t = fmaxf(
            fmaxf(fmaxf(sv[mi][0][0], sv[mi][0][1]),
                  fmaxf(sv[mi][0][2], sv[mi][0][3])),
            fmaxf(fmaxf(sv[mi][1][0], sv[mi][1][1]),
                  fmaxf(sv[mi][1][2], sv[mi][1][3])));
        t = fmaxf(t, __shfl_xor(t, 16));
        t = fmaxf(t, __shfl_xor(t, 32));
        if (__any(t > mrow[mi] + 8.0f)) {  // defer-max: rescale only on growth
          float mn = fmaxf(mrow[mi], t);
          float a = __expf(mrow[mi] - mn);
          mrow[mi] = mn;
          for (int nt = 0; nt < 4; nt++) o[mi][nt] *= a;
          o5[mi] *= a;
        }
        for (int kn = 0; kn < 2; kn++)
          for (int r = 0; r < 4; r++)
            sv[mi][kn][r] = __expf(sv[mi][kn][r] - mrow[mi]);
        unsigned d0 = pack_bf16(sv[mi][0][0], sv[mi][0][1]);
        unsigned d1 = pack_bf16(sv[mi][0][2], sv[mi][0][3]);
        unsigned d2 = pack_bf16(sv[mi][1][0], sv[mi][1][1]);
        unsigned d3 = pack_bf16(sv[mi][1][2], sv[mi][1][3]);
        int row = mi * 16 + c;
        pl[row * 10 + g] = ((u64)d1 << 32) | d0;      // keys 4g..4g+3
        pl[row * 10 + 4 + g] = ((u64)d3 << 32) | d2;  // keys 16+4g..16+4g+3
      }

      asm volatile("" ::: "memory");  // pin P stores before PV loads

      // PV: O = mfma(V, P); l = mfma(1, P). Lane c = q-row for both.
      for (int mi = 0; mi < 2; mi++) {
        union { u64 q[2]; bf16x8 v; } pu;
        pu.q[0] = pl[(mi * 16 + c) * 10 + 2 * g];      // keys 8g..8g+3
        pu.q[1] = pl[(mi * 16 + c) * 10 + 2 * g + 1];  // keys 8g+4..8g+7
        bf16x8 pa = pu.v;
        for (int nt = 0; nt < 4; nt++)
          o[mi][nt] = mfma16(vc[nt], pa, o[mi][nt]);
        o5[mi] = mfma16(vone, pa, o5[mi]);
      }
    }

    // ---- per-wave partials (P region dead now) ----
    float* ow = (float*)wbase;
    float* mw = (float*)(wbase + 8192);
    float* lw = (float*)(wbase + 8320);
    for (int mi = 0; mi < 2; mi++)
      for (int nt = 0; nt < 4; nt++)
        for (int r = 0; r < 4; r++)
          ow[(mi * 16 + c) * 64 + nt * 16 + 4 * g + r] = o[mi][nt][r];
    if (g == 0)
      for (int mi = 0; mi < 2; mi++) {
        mw[mi * 16 + c] = mrow[mi];
        lw[mi * 16 + c] = o5[mi][0];
      }
    __syncthreads();

    // ---- LSE-merge across 8 waves: 512 thr x 4 = 32x64 outputs ----
    for (int i = 0; i < 4; i++) {
      int e = tid + i * 512;
      int row = e >> 6;
      int d = e & 63;
      float M = -1e30f;
      for (int ww = 0; ww < NW; ww++)
        M = fmaxf(M, ((const float*)(smem + ww * 8448 + 8192))[row]);
      float L = 0.f, O = 0.f;
      for (int ww = 0; ww < NW; ww++) {
        float mv = ((const float*)(smem + ww * 8448 + 8192))[row];
        float f = __expf(mv - M);
        L += f * ((const float*)(smem + ww * 8448 + 8320))[row];
        O += f * ((const float*)(smem + ww * 8448))[row * 64 + d];
      }
      out[(rowbase + qb + row) * 64 + d] = O / L;
    }
    __syncthreads();  // merge reads done before next half reuses P region
  }
}

// ---------------------------------------------------------------------------
extern "C" void kernel_launch(void* const* d_in, const int* in_sizes, int n_in,
                              void* d_out, int out_size, void* d_ws, size_t ws_size,
                              hipStream_t stream) {
  const float* x = (const float*)d_in[0];
  const float* Wq = (const float*)d_in[1];
  const float* Wk = (const float*)d_in[2];
  const float* Wv = (const float*)d_in[3];
  float* out = (float*)d_out;

  char* ws = (char*)d_ws;
  unsigned short* Wt = (unsigned short*)(ws);                          // 384 KB
  unsigned short* qws = (unsigned short*)(ws + 393216);                // 2 MB
  unsigned short* kws = (unsigned short*)(ws + 393216 + 2097152);      // 2 MB
  unsigned short* vtws = (unsigned short*)(ws + 393216 + 2 * 2097152); // 2 MB

  prep_w<<<dim3(192), dim3(256), 0, stream>>>(Wq, Wk, Wv, Wt);
  proj_qkv<<<dim3(512), dim3(256), 0, stream>>>(x, Wt, qws, kws, vtws);
  attn_fwd<<<dim3(256), dim3(512), 0, stream>>>(qws, kws, vtws, out);
}